// Round 5
// baseline (255.599 us; speedup 1.0000x reference)
//
#include <hip/hip_runtime.h>

// B=4, N=8, C=256, H=64, W=64, D=512 (single query per batch).
// Algebraic collapse (R1): c read exactly once; K and V never formed.
//   gqk[b,c]  = g[c] * D^-0.5 * (Wkv_upper^T (Wq q_b))[c]
//   dots[n]   = inv_rms[n] * <cp[n,:], gqk[b,:]>   (per pixel)
//   t[c]      = sum_n softmax_n * inv_rms[n] * cp[n,c]
//   out       = Wovg @ t + bo,  Wovg = Wo @ Wkv_lower * diag(g)  (bf16 MFMA)
// R3: launch_bounds(512,4) forced VGPR=64 -> spills -> 141 MB phantom writes.
// R4: spill fixed; ~70 us attn (est.) - per-token 8-wave barrier @2 blocks/CU.
// R5: 1024 blocks x 256 thr (16 px, 4-wave barrier, 4 blocks/CU resident);
//     XCD-aware swizzle so the 4 qg-siblings of a row share an XCD's L2.

typedef __attribute__((ext_vector_type(8))) short short8;
typedef __attribute__((ext_vector_type(4))) float floatx4;

static __device__ __forceinline__ short f2bf(float f) {
  unsigned u = __float_as_uint(f);
  u += 0x7fffu + ((u >> 16) & 1u);   // round-to-nearest-even
  return (short)(u >> 16);
}

// ws: [0,131072) WovgB bf16, A-fragment-linear: element (i,c) at short index
//     ((((i>>4)*8 + (c>>5))*4 + ((c>>3)&3))*16 + (i&15))*8 + (c&7)
//     [131072,135168) gqk f32 [4][256]
__global__ __launch_bounds__(256) void pre_kernel(
    const float* __restrict__ q, const float* __restrict__ g,
    const float* __restrict__ Wq, const float* __restrict__ Wkv,
    const float* __restrict__ Wo, unsigned char* __restrict__ ws) {
  short* WovgB = (short*)ws;
  float* gqk = (float*)(ws + 131072);
  const int blk = blockIdx.x, tid = threadIdx.x;
  if (blk < 64) {
    // 4 i-rows per block: one pass over Wkv lower half serves 4 rows.
    const int c = tid, i0 = blk * 4;
    float s0 = 0.f, s1 = 0.f, s2 = 0.f, s3 = 0.f;
    #pragma unroll 8
    for (int d = 0; d < 512; ++d) {
      const float wv = Wkv[(512 + d) * 256 + c];   // coalesced; L2-resident
      s0 = fmaf(Wo[(i0 + 0) * 512 + d], wv, s0);   // uniform -> scalar loads
      s1 = fmaf(Wo[(i0 + 1) * 512 + d], wv, s1);
      s2 = fmaf(Wo[(i0 + 2) * 512 + d], wv, s2);
      s3 = fmaf(Wo[(i0 + 3) * 512 + d], wv, s3);
    }
    const float gc = g[c];
    const float sv[4] = {s0, s1, s2, s3};
    const int sg = c >> 5, q2 = (c >> 3) & 3, jj = c & 7;
    #pragma unroll
    for (int r = 0; r < 4; ++r) {
      const int i = i0 + r;
      const int it = i >> 4, m = i & 15;
      WovgB[((((it * 8 + sg) * 4 + q2) * 16) + m) * 8 + jj] = f2bf(sv[r] * gc);
    }
  } else {
    const int b = blk - 64;
    __shared__ float qps[512];
    for (int d = tid; d < 512; d += 256) {
      float s = 0.f;
      #pragma unroll 16
      for (int cc = 0; cc < 256; ++cc)
        s = fmaf(Wq[d * 256 + cc], q[b * 256 + cc], s);
      qps[d] = s;
    }
    __syncthreads();
    const int c = tid;
    float s = 0.f;
    #pragma unroll 16
    for (int d = 0; d < 512; ++d)
      s = fmaf(Wkv[d * 256 + c], qps[d], s);
    gqk[b * 256 + c] = s * g[c] * 0.044194173824159216f;  // 512^-0.5
  }
}

// Block = (b, h, qg): 16 px, 256 threads = 4 waves. Wave w owns 64 channels
// [w*64, w*64+64); lane = sub*16+pxl: sub = ch minor (4 ch/instr), pxl = px.
// Grid swizzle: u = bhg*32 + qg*8 + bhm so the 4 qg-siblings of a (b,h) row
// share blockIdx%8 -> same XCD -> complementary 64B halves merge in its L2.
__global__ __launch_bounds__(256) void attn_kernel(
    const float* __restrict__ cin, const float* __restrict__ bo,
    const unsigned char* __restrict__ ws, float* __restrict__ out) {
  const short8* Av = (const short8*)ws;
  const float* gqk = (const float*)(ws + 131072);
  const int u = blockIdx.x;                   // 1024 blocks
  const int bh = ((u >> 5) << 3) | (u & 7);   // b*64 + h
  const int qg = (u >> 3) & 3;
  const int b = bh >> 6, h = bh & 63;
  const int tid = threadIdx.x;
  const int lane = tid & 63, w = tid >> 6;    // w: 0..3
  const int sub = lane >> 4, pxl = lane & 15;

  __shared__ short tB[8][64][8];              // 8 KB, B-fragment-linear
  __shared__ float redS[2][4][16], redD[2][4][16];  // double-buffered

  float rg[16];
  #pragma unroll
  for (int j = 0; j < 16; ++j) rg[j] = gqk[b * 256 + w * 64 + j * 4 + sub];

  float t_reg[16];
  #pragma unroll
  for (int j = 0; j < 16; ++j) t_reg[j] = 0.f;
  float mM = -1e30f, zZ = 0.f;

  // ch = w*64 + j*4 + sub ; px = qg*16 + pxl  (64B segments, 64B-aligned)
  const float* cb = cin + ((size_t)(b * 8) * 256 + w * 64 + sub) * 4096
                        + h * 64 + qg * 16 + pxl;
  float vcur[16], vnxt[16];
  #pragma unroll
  for (int j = 0; j < 16; ++j) vcur[j] = cb[(size_t)j * 16384];  // token 0

  #pragma unroll
  for (int n = 0; n < 8; ++n) {
    float ssq = 0.f, dt = 0.f;
    #pragma unroll
    for (int j = 0; j < 16; ++j) {
      ssq = fmaf(vcur[j], vcur[j], ssq);
      dt = fmaf(vcur[j], rg[j], dt);
    }
    ssq += __shfl_xor(ssq, 16); ssq += __shfl_xor(ssq, 32);  // sum over sub
    dt  += __shfl_xor(dt, 16);  dt  += __shfl_xor(dt, 32);
    if (sub == 0) { redS[n & 1][w][pxl] = ssq; redD[n & 1][w][pxl] = dt; }
    if (n < 7) {                              // prefetch before the barrier
      const float* cp = cb + (size_t)(n + 1) * 1048576;
      #pragma unroll
      for (int j = 0; j < 16; ++j) vnxt[j] = cp[(size_t)j * 16384];
    }
    __syncthreads();                          // 4-wave barrier; 4 blocks/CU
    float S = 0.f, Dt = 0.f;
    #pragma unroll
    for (int ww = 0; ww < 4; ++ww) { S += redS[n & 1][ww][pxl]; Dt += redD[n & 1][ww][pxl]; }
    const float invr = rsqrtf(S * (1.f / 256.f) + 1e-6f);
    const float d = Dt * invr;
    const float mn = fmaxf(mM, d);
    const float al = __expf(mM - mn);         // 0 on first token
    const float e = __expf(d - mn);
    zZ = zZ * al + e;
    mM = mn;
    const float wn = e * invr;
    #pragma unroll
    for (int j = 0; j < 16; ++j) t_reg[j] = fmaf(wn, vcur[j], t_reg[j] * al);
    #pragma unroll
    for (int j = 0; j < 16; ++j) vcur[j] = vnxt[j];
  }

  // write normalized t (bf16) in B-fragment order:
  // reader lane L=(q*16+mm) of k-tile s wants ch=s*32+q*8+jj, px=mm.
  // writer ch = w*64 + j*4 + sub -> s = w*2+(j>>3), k_in = (j&7)*4+sub.
  {
    const float invZ = 1.f / zZ;
    #pragma unroll
    for (int j = 0; j < 16; ++j) {
      const int k_in = (j & 7) * 4 + sub;
      tB[w * 2 + (j >> 3)][(k_in >> 3) * 16 + pxl][k_in & 7] =
          f2bf(t_reg[j] * invZ);
    }
  }
  __syncthreads();

  // phase 3: out[256 i][16 px] = Wovg(bf16) @ t(bf16); wave w -> 64 i-rows
  const int q = lane >> 4, m = lane & 15;
  const short8* Bv = (const short8*)tB;
  floatx4 acc[4];
  #pragma unroll
  for (int it4 = 0; it4 < 4; ++it4) acc[it4] = (floatx4){0.f, 0.f, 0.f, 0.f};
  #pragma unroll
  for (int s = 0; s < 8; ++s) {
    const short8 bf = Bv[s * 64 + lane];
    #pragma unroll
    for (int it4 = 0; it4 < 4; ++it4) {       // A: 16 B/lane, 1 KB/wave, L2
      const short8 a = Av[(((w * 4 + it4) * 8 + s) * 4 + q) * 16 + m];
      acc[it4] = __builtin_amdgcn_mfma_f32_16x16x32_bf16(a, bf, acc[it4], 0, 0, 0);
    }
  }
  // epilogue: D layout col=lane&15(px), row=q*4+r(i)
  float* ob = out + (size_t)b * 1048576 + h * 64 + qg * 16;
  #pragma unroll
  for (int it4 = 0; it4 < 4; ++it4) {
    float bov[4];
    #pragma unroll
    for (int r = 0; r < 4; ++r) bov[r] = bo[(w * 4 + it4) * 16 + q * 4 + r];
    #pragma unroll
    for (int r = 0; r < 4; ++r) {
      const int i = (w * 4 + it4) * 16 + q * 4 + r;
      ob[(size_t)i * 4096 + m] = acc[it4][r] + bov[r];
    }
  }
}

extern "C" void kernel_launch(void* const* d_in, const int* in_sizes, int n_in,
                              void* d_out, int out_size, void* d_ws, size_t ws_size,
                              hipStream_t stream) {
  const float* q   = (const float*)d_in[0];
  const float* c   = (const float*)d_in[1];
  const float* g   = (const float*)d_in[2];
  const float* Wq  = (const float*)d_in[3];
  const float* Wkv = (const float*)d_in[4];
  const float* Wo  = (const float*)d_in[5];
  const float* bo  = (const float*)d_in[6];
  float* out = (float*)d_out;
  unsigned char* ws = (unsigned char*)d_ws;   // needs 135168 bytes
  pre_kernel<<<68, 256, 0, stream>>>(q, g, Wq, Wkv, Wo, ws);
  attn_kernel<<<1024, 256, 0, stream>>>(c, bo, ws, out);
}